// Round 7
// baseline (206.425 us; speedup 1.0000x reference)
//
#include <hip/hip_runtime.h>

#define VOCAB 5000
#define TTOK  16            // tokens per tile (64B of each W row, read-once)
#define JCH   1024          // output cols per chunk -> 4KB contiguous write/visit
#define LSTR  1028          // LDS row stride (pad 4 floats: breaks 4-way write conflict)

typedef float f32x4 __attribute__((ext_vector_type(4)));

// ---------------------------------------------------------------------------
// Single-block counting sort: zero + hist + scan + scatter fused (LDS-based).
// cnt[VOCAB] lives in LDS (20KB). Produces offs[VOCAB+1] and sorted_pk
// (packed (pos << 13) | token).
// ---------------------------------------------------------------------------
__global__ __launch_bounds__(1024) void sort_kernel(
        const int* __restrict__ x, int n,
        int* __restrict__ offs_g, int* __restrict__ sorted_pk) {
    __shared__ int cnt[VOCAB];
    __shared__ int part[1024];
    const int tid = threadIdx.x;

    // zero
    for (int i = tid; i < VOCAB; i += 1024) cnt[i] = 0;
    __syncthreads();

    // histogram (LDS atomics)
    for (int i = tid; i < n; i += 1024) atomicAdd(&cnt[x[i]], 1);
    __syncthreads();

    // exclusive scan: 5 bins per thread + block scan
    const int base = tid * 5;               // 1024*5 = 5120 >= 5000
    int local[5];
    int sum = 0;
#pragma unroll
    for (int k = 0; k < 5; ++k) {
        int idx = base + k;
        int v = (idx < VOCAB) ? cnt[idx] : 0;
        local[k] = sum;
        sum += v;
    }
    part[tid] = sum;
    __syncthreads();
    for (int off = 1; off < 1024; off <<= 1) {
        int v = 0;
        if (tid >= off) v = part[tid - off];
        __syncthreads();
        if (tid >= off) part[tid] += v;
        __syncthreads();
    }
    const int prev = (tid > 0) ? part[tid - 1] : 0;
#pragma unroll
    for (int k = 0; k < 5; ++k) {
        int idx = base + k;
        if (idx < VOCAB) {
            int o = prev + local[k];
            offs_g[idx] = o;
            cnt[idx] = o;                   // becomes the running cursor
        }
    }
    if (tid == 1023) offs_g[VOCAB] = part[1023];
    __syncthreads();

    // scatter
    for (int i = tid; i < n; i += 1024) {
        int t = x[i];
        int slot = atomicAdd(&cnt[t], 1);
        sorted_pk[slot] = (i << 13) | t;    // pos (15b) | token (13b)
    }
}

// ---------------------------------------------------------------------------
// Fused transpose + broadcast gather.
// Block (cidx, tidx): W cols j0..j0+1023 (output cols) x tokens t0..t0+15.
// LDS tile = 16 x 1028 floats = 64.25 KiB  -> 2 blocks/CU: one block's store
// phase overlaps the other's load phase.
// Load: coalesced 64B row-segments of W, each read exactly once device-wide.
// Store: one position per wave per iteration, 4KB contiguous NT write
// (4 full 1KB wave-stores); pk prefetched one iteration ahead.
// ---------------------------------------------------------------------------
__global__ __launch_bounds__(1024) void fused_gather_kernel(
        const float* __restrict__ W,
        const int* __restrict__ offs,
        const int* __restrict__ sorted_pk,
        float* __restrict__ out) {
    __shared__ float tileT[TTOK][LSTR];       // [token][col]
    const int j0 = blockIdx.x * JCH;
    const int t0 = blockIdx.y * TTOK;
    const int jcnt = min(JCH, VOCAB - j0);    // 1024 x4, then 904
    const int tcnt = min(TTOK, VOCAB - t0);   // 16 or 8
    const int tid = threadIdx.x;

    const int begin = offs[t0];
    const int end   = offs[t0 + tcnt];
    if (begin == end) return;                 // no positions use these tokens

    // --- load tile, transposed: tileT[token][col] ---
    const int nc4   = tcnt >> 2;              // f32x4 chunks across tokens: 4 or 2
    const int csh   = (tcnt == TTOK) ? 2 : 1;
    const int cmask = nc4 - 1;
    const int total = jcnt * nc4;
    for (int idx = tid; idx < total; idx += 1024) {
        const int jr = idx >> csh;
        const int c  = idx & cmask;
        f32x4 v = *reinterpret_cast<const f32x4*>(
            W + (size_t)(j0 + jr) * VOCAB + t0 + c * 4);
        tileT[c * 4 + 0][jr] = v.x;
        tileT[c * 4 + 1][jr] = v.y;
        tileT[c * 4 + 2][jr] = v.z;
        tileT[c * 4 + 3][jr] = v.w;
    }
    __syncthreads();

    // --- broadcast write: 16 waves, one position per wave per iteration ---
    const int wid  = tid >> 6;                // 0..15
    const int lane = tid & 63;
    const int f0 = lane * 4;                  // 0..252
    const int nfull    = jcnt >> 8;           // full 256-float chunks: 4 or 3
    const int remlanes = (jcnt & 255) >> 2;   // 0 or 34

    int i = begin + wid;
    if (i >= end) return;
    int pk = sorted_pk[i];
    for (;;) {
        const int inext = i + 16;
        int pk_next = 0;
        if (inext < end) pk_next = sorted_pk[inext];   // prefetch next position

        const int p  = pk >> 13;
        const int tt = (pk & 8191) - t0;
        const float* __restrict__ srow = &tileT[tt][0];
        float* __restrict__ drow = out + (size_t)p * VOCAB + j0;
#pragma unroll
        for (int s = 0; s < 4; ++s) {
            if (s < nfull) {
                f32x4 v = *reinterpret_cast<const f32x4*>(srow + f0 + s * 256);
                __builtin_nontemporal_store(
                    v, reinterpret_cast<f32x4*>(drow + f0 + s * 256));
            }
        }
        if (lane < remlanes) {
            f32x4 v = *reinterpret_cast<const f32x4*>(srow + f0 + nfull * 256);
            __builtin_nontemporal_store(
                v, reinterpret_cast<f32x4*>(drow + f0 + nfull * 256));
        }
        if (inext >= end) break;
        i = inext;
        pk = pk_next;
    }
}

// ---------------------------------------------------------------------------
// Fallback (ws too small): direct column gather, correct but strided reads.
// ---------------------------------------------------------------------------
__global__ void gather_cols_kernel(const float* __restrict__ W,
                                   const int* __restrict__ idx,
                                   float* __restrict__ out) {
    const int p = blockIdx.x;
    const int token = idx[p];
    for (int v = threadIdx.x; v < VOCAB; v += blockDim.x)
        out[(size_t)p * VOCAB + v] = W[(size_t)v * VOCAB + token];
}

extern "C" void kernel_launch(void* const* d_in, const int* in_sizes, int n_in,
                              void* d_out, int out_size, void* d_ws, size_t ws_size,
                              hipStream_t stream) {
    const int*   x = (const int*)d_in[0];     // [B*T] token ids
    const float* W = (const float*)d_in[1];   // [VOCAB, VOCAB] fp32
    float* out = (float*)d_out;               // [B*T, VOCAB] fp32
    const int npos = in_sizes[0];             // 32768

    // ws layout: offs[V+1] | sorted_pk[npos]
    int* offs   = (int*)d_ws;
    int* sorted = offs + VOCAB + 1;
    const size_t need = (size_t)(VOCAB + 1 + npos) * sizeof(int);

    if (ws_size >= need) {
        sort_kernel<<<1, 1024, 0, stream>>>(x, npos, offs, sorted);
        dim3 grid((VOCAB + JCH - 1) / JCH, (VOCAB + TTOK - 1) / TTOK);  // 5 x 313
        fused_gather_kernel<<<grid, 1024, 0, stream>>>(W, offs, sorted, out);
    } else {
        gather_cols_kernel<<<npos, 256, 0, stream>>>(W, x, out);
    }
}

// Round 8
// 204.383 us; speedup vs baseline: 1.0100x; 1.0100x over previous
//
#include <hip/hip_runtime.h>

#define VOCAB 5000
#define TTOK  16            // tokens per tile (64B of each W row)
#define JCH   2048          // output cols per chunk -> 8KB contiguous write/visit

typedef float f32x4 __attribute__((ext_vector_type(4)));

// ---------------------------------------------------------------------------
// Counting sort of positions by token id (packed: (pos << 13) | token).
// ---------------------------------------------------------------------------
__global__ void zero_kernel(int* __restrict__ ptr, int n) {
    int i = blockIdx.x * blockDim.x + threadIdx.x;
    if (i < n) ptr[i] = 0;
}

__global__ void hist_kernel(const int* __restrict__ x, int* __restrict__ counts, int n) {
    int i = blockIdx.x * blockDim.x + threadIdx.x;
    if (i < n) atomicAdd(&counts[x[i]], 1);
}

// Single-block exclusive scan over VOCAB counters -> offs[0..VOCAB].
__global__ void scan_kernel(const int* __restrict__ counts, int* __restrict__ offs) {
    __shared__ int part[1024];
    const int tid = threadIdx.x;
    const int base = tid * 5;               // 1024*5 = 5120 >= 5000
    int local[5];
    int sum = 0;
#pragma unroll
    for (int k = 0; k < 5; ++k) {
        int idx = base + k;
        int v = (idx < VOCAB) ? counts[idx] : 0;
        local[k] = sum;
        sum += v;
    }
    part[tid] = sum;
    __syncthreads();
    for (int off = 1; off < 1024; off <<= 1) {
        int v = 0;
        if (tid >= off) v = part[tid - off];
        __syncthreads();
        if (tid >= off) part[tid] += v;
        __syncthreads();
    }
    const int prev = (tid > 0) ? part[tid - 1] : 0;
#pragma unroll
    for (int k = 0; k < 5; ++k) {
        int idx = base + k;
        if (idx < VOCAB) offs[idx] = prev + local[k];
    }
    if (tid == 1023) offs[VOCAB] = part[1023];
}

__global__ void scatter_kernel(const int* __restrict__ x, const int* __restrict__ offs,
                               int* __restrict__ cursor, int* __restrict__ sorted_pk, int n) {
    int i = blockIdx.x * blockDim.x + threadIdx.x;
    if (i < n) {
        int t = x[i];
        int d = atomicAdd(&cursor[t], 1);
        sorted_pk[offs[t] + d] = (i << 13) | t;   // pos (15b) | token (13b)
    }
}

// ---------------------------------------------------------------------------
// Fused transpose + broadcast gather.
// Block (cidx, tidx): W cols j0..j0+2047 (output cols) x tokens t0..t0+15.
// LDS tile = 16 x 2048 floats = 128 KiB (1 block/CU, 16 waves).
// Load: coalesced 64B row-segments of W, read exactly once device-wide.
// Store: one position per wave per iteration, 8KB contiguous CACHED write
// (8 full 1KB wave-stores); pk prefetched one iteration ahead.
// NOTE: W has no cache reuse (each line read once) -> no reason to protect
// L2/L3 with NT stores; plain cached stores match the fill kernel's path.
// ---------------------------------------------------------------------------
__global__ __launch_bounds__(1024) void fused_gather_kernel(
        const float* __restrict__ W,
        const int* __restrict__ offs,
        const int* __restrict__ sorted_pk,
        float* __restrict__ out) {
    __shared__ float tileT[TTOK][JCH];        // [token][col], 128 KiB
    const int j0 = blockIdx.x * JCH;
    const int t0 = blockIdx.y * TTOK;
    const int jcnt = min(JCH, VOCAB - j0);    // 2048, 2048, 904
    const int tcnt = min(TTOK, VOCAB - t0);   // 16 or 8
    const int tid = threadIdx.x;

    const int begin = offs[t0];
    const int end   = offs[t0 + tcnt];
    if (begin == end) return;                 // no positions use these tokens

    // --- load tile, transposed: tileT[token][col] ---
    const int nc4   = tcnt >> 2;              // f32x4 chunks across tokens: 4 or 2
    const int csh   = (tcnt == TTOK) ? 2 : 1;
    const int cmask = nc4 - 1;
    const int total = jcnt * nc4;
    for (int idx = tid; idx < total; idx += 1024) {
        const int jr = idx >> csh;
        const int c  = idx & cmask;
        f32x4 v = *reinterpret_cast<const f32x4*>(
            W + (size_t)(j0 + jr) * VOCAB + t0 + c * 4);
        tileT[c * 4 + 0][jr] = v.x;
        tileT[c * 4 + 1][jr] = v.y;
        tileT[c * 4 + 2][jr] = v.z;
        tileT[c * 4 + 3][jr] = v.w;
    }
    __syncthreads();

    // --- broadcast write: 16 waves, one position per wave per iteration ---
    const int wid  = tid >> 6;                // 0..15
    const int lane = tid & 63;
    const int f0 = lane * 4;                  // 0..252
    const int nfull    = jcnt >> 8;           // full 256-float chunks: 8 or 3
    const int remlanes = (jcnt & 255) >> 2;   // 0 or 34

    int i = begin + wid;
    if (i >= end) return;
    int pk = sorted_pk[i];
    for (;;) {
        const int inext = i + 16;
        int pk_next = 0;
        if (inext < end) pk_next = sorted_pk[inext];   // prefetch next position

        const int p  = pk >> 13;
        const int tt = (pk & 8191) - t0;
        const float* __restrict__ srow = &tileT[tt][0];
        float* __restrict__ drow = out + (size_t)p * VOCAB + j0;
#pragma unroll
        for (int s = 0; s < 8; ++s) {
            if (s < nfull) {
                f32x4 v = *reinterpret_cast<const f32x4*>(srow + f0 + s * 256);
                *reinterpret_cast<f32x4*>(drow + f0 + s * 256) = v;
            }
        }
        if (lane < remlanes) {
            f32x4 v = *reinterpret_cast<const f32x4*>(srow + f0 + nfull * 256);
            *reinterpret_cast<f32x4*>(drow + f0 + nfull * 256) = v;
        }
        if (inext >= end) break;
        i = inext;
        pk = pk_next;
    }
}

// ---------------------------------------------------------------------------
// Fallback (ws too small): direct column gather, correct but strided reads.
// ---------------------------------------------------------------------------
__global__ void gather_cols_kernel(const float* __restrict__ W,
                                   const int* __restrict__ idx,
                                   float* __restrict__ out) {
    const int p = blockIdx.x;
    const int token = idx[p];
    for (int v = threadIdx.x; v < VOCAB; v += blockDim.x)
        out[(size_t)p * VOCAB + v] = W[(size_t)v * VOCAB + token];
}

extern "C" void kernel_launch(void* const* d_in, const int* in_sizes, int n_in,
                              void* d_out, int out_size, void* d_ws, size_t ws_size,
                              hipStream_t stream) {
    const int*   x = (const int*)d_in[0];     // [B*T] token ids
    const float* W = (const float*)d_in[1];   // [VOCAB, VOCAB] fp32
    float* out = (float*)d_out;               // [B*T, VOCAB] fp32
    const int npos = in_sizes[0];             // 32768

    // ws layout: counts[V] | cursor[V] | offs[V+1] | sorted_pk[npos]
    int* counts = (int*)d_ws;
    int* cursor = counts + VOCAB;
    int* offs   = cursor + VOCAB;
    int* sorted = offs + VOCAB + 1;
    const size_t need = (size_t)(3 * VOCAB + 1 + npos) * sizeof(int);

    if (ws_size >= need) {
        zero_kernel<<<(2 * VOCAB + 255) / 256, 256, 0, stream>>>(counts, 2 * VOCAB);
        hist_kernel<<<(npos + 255) / 256, 256, 0, stream>>>(x, counts, npos);
        scan_kernel<<<1, 1024, 0, stream>>>(counts, offs);
        scatter_kernel<<<(npos + 255) / 256, 256, 0, stream>>>(x, offs, cursor, sorted, npos);
        dim3 grid((VOCAB + JCH - 1) / JCH, (VOCAB + TTOK - 1) / TTOK);  // 3 x 313
        fused_gather_kernel<<<grid, 1024, 0, stream>>>(W, offs, sorted, out);
    } else {
        gather_cols_kernel<<<npos, 256, 0, stream>>>(W, x, out);
    }
}

// Round 9
// 194.331 us; speedup vs baseline: 1.0622x; 1.0517x over previous
//
#include <hip/hip_runtime.h>

#define VOCAB 5000
#define TTOK  16            // tokens per tile (64B of each W row, read-once)
#define JCH   1280          // output cols per chunk -> 5KB write/visit; LDS=80KiB -> 2 blocks/CU

typedef float f32x4 __attribute__((ext_vector_type(4)));

// ---------------------------------------------------------------------------
// Counting sort of positions by token id (packed: (pos << 13) | token).
// ---------------------------------------------------------------------------
__global__ void zero_kernel(int* __restrict__ ptr, int n) {
    int i = blockIdx.x * blockDim.x + threadIdx.x;
    if (i < n) ptr[i] = 0;
}

__global__ void hist_kernel(const int* __restrict__ x, int* __restrict__ counts, int n) {
    int i = blockIdx.x * blockDim.x + threadIdx.x;
    if (i < n) atomicAdd(&counts[x[i]], 1);
}

// Single-block exclusive scan over VOCAB counters -> offs[0..VOCAB].
__global__ void scan_kernel(const int* __restrict__ counts, int* __restrict__ offs) {
    __shared__ int part[1024];
    const int tid = threadIdx.x;
    const int base = tid * 5;               // 1024*5 = 5120 >= 5000
    int local[5];
    int sum = 0;
#pragma unroll
    for (int k = 0; k < 5; ++k) {
        int idx = base + k;
        int v = (idx < VOCAB) ? counts[idx] : 0;
        local[k] = sum;
        sum += v;
    }
    part[tid] = sum;
    __syncthreads();
    for (int off = 1; off < 1024; off <<= 1) {
        int v = 0;
        if (tid >= off) v = part[tid - off];
        __syncthreads();
        if (tid >= off) part[tid] += v;
        __syncthreads();
    }
    const int prev = (tid > 0) ? part[tid - 1] : 0;
#pragma unroll
    for (int k = 0; k < 5; ++k) {
        int idx = base + k;
        if (idx < VOCAB) offs[idx] = prev + local[k];
    }
    if (tid == 1023) offs[VOCAB] = part[1023];
}

__global__ void scatter_kernel(const int* __restrict__ x, const int* __restrict__ offs,
                               int* __restrict__ cursor, int* __restrict__ sorted_pk, int n) {
    int i = blockIdx.x * blockDim.x + threadIdx.x;
    if (i < n) {
        int t = x[i];
        int d = atomicAdd(&cursor[t], 1);
        sorted_pk[offs[t] + d] = (i << 13) | t;   // pos (15b) | token (13b)
    }
}

// ---------------------------------------------------------------------------
// Fused transpose + broadcast gather.
// Block (cidx, tidx): W cols j0..j0+1279 (output cols) x tokens t0..t0+15.
// LDS tile = 16 x 1280 floats = 80 KiB -> 2 blocks/CU: one block's store
// phase (HBM-write-bound) hides the other's load phase.
// Load: coalesced 64B row-segments of W, read exactly once device-wide.
// Store: one position per wave per iteration, 5KB contiguous NT write
// (5 full 1KB wave-stores); pk prefetched one iteration ahead.
// NT stores: R6 vs R8 A/B showed NT worth ~18us on this scattered write
// stream (avoids L2/L3 write-allocate churn).
// ---------------------------------------------------------------------------
__global__ __launch_bounds__(1024) void fused_gather_kernel(
        const float* __restrict__ W,
        const int* __restrict__ offs,
        const int* __restrict__ sorted_pk,
        float* __restrict__ out) {
    __shared__ float tileT[TTOK][JCH];        // [token][col], 80 KiB
    const int j0 = blockIdx.x * JCH;
    const int t0 = blockIdx.y * TTOK;
    const int jcnt = min(JCH, VOCAB - j0);    // 1280 x3, then 1160
    const int tcnt = min(TTOK, VOCAB - t0);   // 16 or 8
    const int tid = threadIdx.x;

    const int begin = offs[t0];
    const int end   = offs[t0 + tcnt];
    if (begin == end) return;                 // no positions use these tokens

    // --- load tile, transposed: tileT[token][col] ---
    const int nc4   = tcnt >> 2;              // f32x4 chunks across tokens: 4 or 2
    const int csh   = (tcnt == TTOK) ? 2 : 1;
    const int cmask = nc4 - 1;
    const int total = jcnt * nc4;
    for (int idx = tid; idx < total; idx += 1024) {
        const int jr = idx >> csh;
        const int c  = idx & cmask;
        f32x4 v = *reinterpret_cast<const f32x4*>(
            W + (size_t)(j0 + jr) * VOCAB + t0 + c * 4);
        tileT[c * 4 + 0][jr] = v.x;
        tileT[c * 4 + 1][jr] = v.y;
        tileT[c * 4 + 2][jr] = v.z;
        tileT[c * 4 + 3][jr] = v.w;
    }
    __syncthreads();

    // --- broadcast write: 16 waves, one position per wave per iteration ---
    const int wid  = tid >> 6;                // 0..15
    const int lane = tid & 63;
    const int f0 = lane * 4;                  // 0..252
    const int nfull    = jcnt >> 8;           // full 256-float chunks: 5 or 4
    const int remlanes = (jcnt & 255) >> 2;   // 0 or 34

    int i = begin + wid;
    if (i >= end) return;
    int pk = sorted_pk[i];
    for (;;) {
        const int inext = i + 16;
        int pk_next = 0;
        if (inext < end) pk_next = sorted_pk[inext];   // prefetch next position

        const int p  = pk >> 13;
        const int tt = (pk & 8191) - t0;
        const float* __restrict__ srow = &tileT[tt][0];
        float* __restrict__ drow = out + (size_t)p * VOCAB + j0;
#pragma unroll
        for (int s = 0; s < 5; ++s) {
            if (s < nfull) {
                f32x4 v = *reinterpret_cast<const f32x4*>(srow + f0 + s * 256);
                __builtin_nontemporal_store(
                    v, reinterpret_cast<f32x4*>(drow + f0 + s * 256));
            }
        }
        if (lane < remlanes) {
            f32x4 v = *reinterpret_cast<const f32x4*>(srow + f0 + nfull * 256);
            __builtin_nontemporal_store(
                v, reinterpret_cast<f32x4*>(drow + f0 + nfull * 256));
        }
        if (inext >= end) break;
        i = inext;
        pk = pk_next;
    }
}

// ---------------------------------------------------------------------------
// Fallback (ws too small): direct column gather, correct but strided reads.
// ---------------------------------------------------------------------------
__global__ void gather_cols_kernel(const float* __restrict__ W,
                                   const int* __restrict__ idx,
                                   float* __restrict__ out) {
    const int p = blockIdx.x;
    const int token = idx[p];
    for (int v = threadIdx.x; v < VOCAB; v += blockDim.x)
        out[(size_t)p * VOCAB + v] = W[(size_t)v * VOCAB + token];
}

extern "C" void kernel_launch(void* const* d_in, const int* in_sizes, int n_in,
                              void* d_out, int out_size, void* d_ws, size_t ws_size,
                              hipStream_t stream) {
    const int*   x = (const int*)d_in[0];     // [B*T] token ids
    const float* W = (const float*)d_in[1];   // [VOCAB, VOCAB] fp32
    float* out = (float*)d_out;               // [B*T, VOCAB] fp32
    const int npos = in_sizes[0];             // 32768

    // ws layout: counts[V] | cursor[V] | offs[V+1] | sorted_pk[npos]
    int* counts = (int*)d_ws;
    int* cursor = counts + VOCAB;
    int* offs   = cursor + VOCAB;
    int* sorted = offs + VOCAB + 1;
    const size_t need = (size_t)(3 * VOCAB + 1 + npos) * sizeof(int);

    if (ws_size >= need) {
        zero_kernel<<<(2 * VOCAB + 255) / 256, 256, 0, stream>>>(counts, 2 * VOCAB);
        hist_kernel<<<(npos + 255) / 256, 256, 0, stream>>>(x, counts, npos);
        scan_kernel<<<1, 1024, 0, stream>>>(counts, offs);
        scatter_kernel<<<(npos + 255) / 256, 256, 0, stream>>>(x, offs, cursor, sorted, npos);
        dim3 grid((VOCAB + JCH - 1) / JCH, (VOCAB + TTOK - 1) / TTOK);  // 4 x 313
        fused_gather_kernel<<<grid, 1024, 0, stream>>>(W, offs, sorted, out);
    } else {
        gather_cols_kernel<<<npos, 256, 0, stream>>>(W, x, out);
    }
}